// Round 8
// baseline (252.188 us; speedup 1.0000x reference)
//
#include <hip/hip_runtime.h>
#include <hip/hip_bf16.h>

#define NNODES 100000
#define DFEAT 128
#define NBKT 8
#define STRIPE 12500            // nodes per dst bucket (100000/8)
#define BUCKET_CAP 416000       // ~400000 expected + big slack
#define CHUNK 4096
#define SUBNODES 64             // nodes per sub-bucket
#define NSUB 196                // ceil(12500/64)
#define SUBCAP 2560             // mean 2041 + 11.5 sigma
#define NSB (NBKT * NSUB)       // 1568 sub-buckets

typedef short bf16x8 __attribute__((ext_vector_type(8)));
typedef float f32x4  __attribute__((ext_vector_type(4)));

__device__ __forceinline__ unsigned short f2bf(float f) {
    unsigned u = __builtin_bit_cast(unsigned, f);
    return (unsigned short)((u + 0x7fffu + ((u >> 16) & 1u)) >> 16);
}

// ---------------------------------------------------------------------------
// X fp32 -> bf16 (packed), 8 elems/thread
// ---------------------------------------------------------------------------
__global__ __launch_bounds__(256)
void x2bf_kernel(const float4* __restrict__ X, uint4* __restrict__ Xb, int n8) {
    int i = blockIdx.x * 256 + threadIdx.x;
    if (i >= n8) return;
    float4 a = X[2 * i], b = X[2 * i + 1];
    uint4 o;
    o.x = f2bf(a.x) | ((unsigned)f2bf(a.y) << 16);
    o.y = f2bf(a.z) | ((unsigned)f2bf(a.w) << 16);
    o.z = f2bf(b.x) | ((unsigned)f2bf(b.y) << 16);
    o.w = f2bf(b.z) | ((unsigned)f2bf(b.w) << 16);
    Xb[i] = o;
}

// ---------------------------------------------------------------------------
// W[k][n] fp32 -> Wt[n][k] bf16, both weight matrices in one launch
// ---------------------------------------------------------------------------
__global__ __launch_bounds__(256)
void wprep(const float* __restrict__ w1, const float* __restrict__ w2,
           unsigned short* __restrict__ w1t, unsigned short* __restrict__ w2t) {
    int i = blockIdx.x * 256 + threadIdx.x;           // 0..32767
    const float* w = (i < 16384) ? w1 : w2;
    unsigned short* o = (i < 16384) ? w1t : w2t;
    int j = i & 16383;
    int n = j >> 7, k = j & 127;
    o[n * 128 + k] = f2bf(w[k * 128 + n]);
}

// ---------------------------------------------------------------------------
// Pass A: partition edges into 8 dst-stripe buckets (validated R5/R6).
// Entry: src | (dst - b*STRIPE)<<17. LDS reorder -> coalesced segment flush.
// ---------------------------------------------------------------------------
__global__ __launch_bounds__(256)
void partition_edges(const int* __restrict__ dst, const int* __restrict__ src,
                     int* __restrict__ bcur, unsigned* __restrict__ bedges,
                     int nE) {
    __shared__ unsigned sbuf[CHUNK];
    __shared__ int scnt[NBKT];
    __shared__ int sbase[NBKT];
    __shared__ int scur[NBKT];
    __shared__ int gbase[NBKT];

    const int tid = threadIdx.x;
    const long long e0 = (long long)blockIdx.x * CHUNK;
    const int n = (int)min((long long)CHUNK, (long long)nE - e0);
    if (n <= 0) return;

    if (tid < NBKT) scnt[tid] = 0;
    __syncthreads();

    unsigned ent[CHUNK / 256];
    int bkt[CHUNK / 256];
#pragma unroll
    for (int j = 0; j < CHUNK / 256; ++j) {
        int i = tid + j * 256;                    // coalesced
        if (i < n) {
            int d = dst[e0 + i];
            int s = src[e0 + i];
            int b = d / STRIPE;                   // 0..7 (const divisor)
            ent[j] = (unsigned)s | ((unsigned)(d - b * STRIPE) << 17);
            bkt[j] = b;
            atomicAdd(&scnt[b], 1);
        } else bkt[j] = -1;
    }
    __syncthreads();

    if (tid == 0) {
        int run = 0;
        for (int b = 0; b < NBKT; ++b) { sbase[b] = run; scur[b] = run; run += scnt[b]; }
    }
    __syncthreads();

#pragma unroll
    for (int j = 0; j < CHUNK / 256; ++j)
        if (bkt[j] >= 0) {
            int p = atomicAdd(&scur[bkt[j]], 1);
            sbuf[p] = ent[j];
        }
    if (tid < NBKT) gbase[tid] = atomicAdd(&bcur[tid], scnt[tid]);
    __syncthreads();

    for (int i = tid; i < n; i += 256) {
        int b = 0;
        while (b < NBKT - 1 && i >= sbase[b + 1]) ++b;
        bedges[(size_t)b * BUCKET_CAP + gbase[b] + (i - sbase[b])] = sbuf[i];
    }
}

// ---------------------------------------------------------------------------
// Pass B: split each bucket into 196 sub-buckets of 64 nodes (key dst_local>>6).
// XCD b reads/writes only its own bucket region -> stays L2-local.
// ---------------------------------------------------------------------------
__global__ __launch_bounds__(256)
void partition_sub(const unsigned* __restrict__ bedges, const int* __restrict__ bcur,
                   int* __restrict__ scur2, unsigned* __restrict__ sub_edges) {
    __shared__ unsigned sbuf[CHUNK];
    __shared__ int scnt[NSUB];
    __shared__ int sbase[NSUB + 1];
    __shared__ int scur[NSUB];
    __shared__ int gbase[NSUB];

    const int b   = blockIdx.x & (NBKT - 1);
    const int blk = blockIdx.x >> 3;
    const int sz  = bcur[b];
    const int e0  = blk * CHUNK;
    if (e0 >= sz) return;
    const int n = min(CHUNK, sz - e0);
    const unsigned* p = bedges + (size_t)b * BUCKET_CAP + e0;
    const int tid = threadIdx.x;

    for (int i = tid; i < NSUB; i += 256) scnt[i] = 0;
    __syncthreads();

    unsigned ent[CHUNK / 256];
    int sbk[CHUNK / 256];
#pragma unroll
    for (int j = 0; j < CHUNK / 256; ++j) {
        int i = tid + j * 256;
        if (i < n) {
            unsigned v = p[i];
            int s = (int)(v >> 23);               // dst_local>>6, 0..195
            ent[j] = v;
            sbk[j] = s;
            atomicAdd(&scnt[s], 1);
        } else sbk[j] = -1;
    }
    __syncthreads();

    if (tid == 0) {
        int run = 0;
        for (int s = 0; s < NSUB; ++s) { sbase[s] = run; scur[s] = run; run += scnt[s]; }
        sbase[NSUB] = run;
    }
    __syncthreads();

#pragma unroll
    for (int j = 0; j < CHUNK / 256; ++j)
        if (sbk[j] >= 0) {
            int pos = atomicAdd(&scur[sbk[j]], 1);
            sbuf[pos] = ent[j];
        }
    if (tid < NSUB) gbase[tid] = atomicAdd(&scur2[b * NSUB + tid], scnt[tid]);
    __syncthreads();

    for (int s = 0; s < NSUB; ++s) {
        int lo = sbase[s], hi = sbase[s + 1];
        int g0 = gbase[s];
        unsigned* q = sub_edges + (size_t)(b * NSUB + s) * SUBCAP;
        for (int i = lo + tid; i < hi; i += 256) {
            int o = g0 + (i - lo);
            if (o < SUBCAP) q[o] = sbuf[i];       // statistical overflow guard
        }
    }
}

// ---------------------------------------------------------------------------
// Pass C: fused counting-sort + aggregation, one block per 64-node sub-bucket.
// LDS ~11 KB; __launch_bounds__(256,8) caps VGPR<=64 so 8 blocks/CU is
// reachable (R6 ran at 15.6% occupancy, 68 VGPR -> 16-wave cliff).
// ---------------------------------------------------------------------------
__device__ __forceinline__ void bfadd(float* acc, uint4 v) {
    acc[0] += __builtin_bit_cast(float, v.x << 16);
    acc[1] += __builtin_bit_cast(float, v.x & 0xffff0000u);
    acc[2] += __builtin_bit_cast(float, v.y << 16);
    acc[3] += __builtin_bit_cast(float, v.y & 0xffff0000u);
    acc[4] += __builtin_bit_cast(float, v.z << 16);
    acc[5] += __builtin_bit_cast(float, v.z & 0xffff0000u);
    acc[6] += __builtin_bit_cast(float, v.w << 16);
    acc[7] += __builtin_bit_cast(float, v.w & 0xffff0000u);
}

__global__ __launch_bounds__(256, 8)
void sort_aggregate(const unsigned* __restrict__ sub_edges,
                    const int* __restrict__ scur2,
                    const uint4* __restrict__ Xb, uint4* __restrict__ convb) {
    __shared__ unsigned srt[SUBCAP];
    __shared__ int cnt[SUBNODES];
    __shared__ int off[SUBNODES + 1];
    __shared__ int cur[SUBNODES];

    const int b  = blockIdx.x & (NBKT - 1);      // reader XCD == writer XCD
    const int j  = blockIdx.x >> 3;              // 0..195
    const int sb = b * NSUB + j;
    const int tid = threadIdx.x;
    const int sz = min(scur2[sb], SUBCAP);
    const int nodeBase = b * STRIPE + j * SUBNODES;
    const int nLoc = min(SUBNODES, STRIPE - j * SUBNODES);  // 64 (last: 20)
    const unsigned* p = sub_edges + (size_t)sb * SUBCAP;

    if (tid < SUBNODES) cnt[tid] = 0;
    __syncthreads();
    for (int i = tid; i < sz; i += 256)
        atomicAdd(&cnt[(p[i] >> 17) & 63], 1);
    __syncthreads();

    // single-wave shuffle scan over 64 bins
    if (tid < 64) {
        int v = cnt[tid];
        int s = v;
#pragma unroll
        for (int d = 1; d < 64; d <<= 1) {
            int t = __shfl_up(s, d, 64);
            if (tid >= d) s += t;
        }
        off[tid + 1] = s;        // inclusive
        cur[tid] = s - v;        // exclusive
        if (tid == 0) off[0] = 0;
    }
    __syncthreads();

    // scatter into sorted order (LDS only)
    for (int i = tid; i < sz; i += 256) {
        unsigned v = p[i];
        int pos = atomicAdd(&cur[(v >> 17) & 63], 1);
        srt[pos] = v & 0x1FFFFu;
    }
    __syncthreads();

    // aggregate: 16 groups x 16 lanes; group g handles nodes g, g+16, ...
    const int grp = tid >> 4, lane = tid & 15;
    for (int n0 = grp; n0 < nLoc; n0 += 16) {
        int node = nodeBase + n0;
        float acc[8];
#pragma unroll
        for (int q = 0; q < 8; ++q) acc[q] = 0.f;
        bfadd(acc, Xb[(size_t)node * 16 + lane]);    // self term (eps=0)

        int e = off[n0], end = off[n0 + 1];
        for (; e + 4 <= end; e += 4) {
            int s0 = srt[e + 0], s1 = srt[e + 1], s2 = srt[e + 2], s3 = srt[e + 3];
            uint4 v0 = Xb[(size_t)s0 * 16 + lane];
            uint4 v1 = Xb[(size_t)s1 * 16 + lane];
            uint4 v2 = Xb[(size_t)s2 * 16 + lane];
            uint4 v3 = Xb[(size_t)s3 * 16 + lane];
            bfadd(acc, v0); bfadd(acc, v1); bfadd(acc, v2); bfadd(acc, v3);
        }
        for (; e < end; ++e)
            bfadd(acc, Xb[(size_t)srt[e] * 16 + lane]);

        uint4 o;
        o.x = f2bf(acc[0]) | ((unsigned)f2bf(acc[1]) << 16);
        o.y = f2bf(acc[2]) | ((unsigned)f2bf(acc[3]) << 16);
        o.z = f2bf(acc[4]) | ((unsigned)f2bf(acc[5]) << 16);
        o.w = f2bf(acc[6]) | ((unsigned)f2bf(acc[7]) << 16);
        convb[(size_t)node * 16 + lane] = o;
    }
}

// ---------------------------------------------------------------------------
// Fused MLP via bf16 MFMA (validated R4-R6)
// ---------------------------------------------------------------------------
#define TM 128

__global__ __launch_bounds__(256, 1)
void mlp_fused(const unsigned short* __restrict__ convb,
               const unsigned short* __restrict__ w1t, const float* __restrict__ b1,
               const unsigned short* __restrict__ w2t, const float* __restrict__ b2,
               float* __restrict__ out, int N) {
    __shared__ unsigned short sA[TM][136];
    __shared__ unsigned short sW[128][136];
    __shared__ unsigned short sH[TM][136];

    const int tid  = threadIdx.x;
    const int row0 = blockIdx.x * TM;

    for (int i = tid; i < TM * 16; i += 256) {
        int r = i >> 4, c = i & 15;
        uint4 v = make_uint4(0, 0, 0, 0);
        if (row0 + r < N) v = ((const uint4*)convb)[(size_t)(row0 + r) * 16 + c];
        *(uint4*)&sA[r][c * 8] = v;
    }
    for (int i = tid; i < 128 * 16; i += 256) {
        int r = i >> 4, c = i & 15;
        *(uint4*)&sW[r][c * 8] = ((const uint4*)w1t)[r * 16 + c];
    }
    __syncthreads();

    const int lane = tid & 63;
    const int lrow = lane & 15;
    const int kgrp = lane >> 4;
    const int m0   = (tid >> 6) * 32;

    float bias[8];
#pragma unroll
    for (int nf = 0; nf < 8; ++nf) bias[nf] = b1[nf * 16 + lrow];

    f32x4 acc[2][8] = {};
#pragma unroll
    for (int kk = 0; kk < 128; kk += 32) {
        bf16x8 a0 = *(const bf16x8*)&sA[m0 + lrow][kk + kgrp * 8];
        bf16x8 a1 = *(const bf16x8*)&sA[m0 + 16 + lrow][kk + kgrp * 8];
#pragma unroll
        for (int nf = 0; nf < 8; ++nf) {
            bf16x8 b = *(const bf16x8*)&sW[nf * 16 + lrow][kk + kgrp * 8];
            acc[0][nf] = __builtin_amdgcn_mfma_f32_16x16x32_bf16(a0, b, acc[0][nf], 0, 0, 0);
            acc[1][nf] = __builtin_amdgcn_mfma_f32_16x16x32_bf16(a1, b, acc[1][nf], 0, 0, 0);
        }
    }

#pragma unroll
    for (int mf = 0; mf < 2; ++mf)
#pragma unroll
        for (int nf = 0; nf < 8; ++nf)
#pragma unroll
            for (int r = 0; r < 4; ++r) {
                int row = m0 + mf * 16 + kgrp * 4 + r;
                int col = nf * 16 + lrow;
                float h = fmaxf(acc[mf][nf][r] + bias[nf], 0.f);
                sH[row][col] = f2bf(h);
            }

    __syncthreads();

    for (int i = tid; i < 128 * 16; i += 256) {
        int r = i >> 4, c = i & 15;
        *(uint4*)&sW[r][c * 8] = ((const uint4*)w2t)[r * 16 + c];
    }
#pragma unroll
    for (int nf = 0; nf < 8; ++nf) bias[nf] = b2[nf * 16 + lrow];
#pragma unroll
    for (int mf = 0; mf < 2; ++mf)
#pragma unroll
        for (int nf = 0; nf < 8; ++nf) acc[mf][nf] = (f32x4){0.f, 0.f, 0.f, 0.f};
    __syncthreads();

#pragma unroll
    for (int kk = 0; kk < 128; kk += 32) {
        bf16x8 a0 = *(const bf16x8*)&sH[m0 + lrow][kk + kgrp * 8];
        bf16x8 a1 = *(const bf16x8*)&sH[m0 + 16 + lrow][kk + kgrp * 8];
#pragma unroll
        for (int nf = 0; nf < 8; ++nf) {
            bf16x8 b = *(const bf16x8*)&sW[nf * 16 + lrow][kk + kgrp * 8];
            acc[0][nf] = __builtin_amdgcn_mfma_f32_16x16x32_bf16(a0, b, acc[0][nf], 0, 0, 0);
            acc[1][nf] = __builtin_amdgcn_mfma_f32_16x16x32_bf16(a1, b, acc[1][nf], 0, 0, 0);
        }
    }

#pragma unroll
    for (int mf = 0; mf < 2; ++mf)
#pragma unroll
        for (int nf = 0; nf < 8; ++nf)
#pragma unroll
            for (int r = 0; r < 4; ++r) {
                int row = row0 + m0 + mf * 16 + kgrp * 4 + r;
                int col = nf * 16 + lrow;
                if (row < N)
                    out[(size_t)row * 128 + col] = fmaxf(acc[mf][nf][r] + bias[nf], 0.f);
            }
}

// ---------------------------------------------------------------------------
extern "C" void kernel_launch(void* const* d_in, const int* in_sizes, int n_in,
                              void* d_out, int out_size, void* d_ws, size_t ws_size,
                              hipStream_t stream) {
    const float* X    = (const float*)d_in[0];
    const int*   refA = (const int*)d_in[1];   // dst per edge
    const int*   refB = (const int*)d_in[2];   // src per edge
    const float* w1   = (const float*)d_in[3];
    const float* b1   = (const float*)d_in[4];
    const float* w2   = (const float*)d_in[5];
    const float* b2   = (const float*)d_in[6];
    float* out = (float*)d_out;

    const int nNodes = in_sizes[0] / DFEAT;    // 100000
    const int nE     = in_sizes[1];            // 3200000

    // Workspace layout with liveness-based aliasing:
    //   Xb       : 25.6 MB  (live: x2bf -> sort_aggregate)
    //   convb    : 25.6 MB  -- ALIASES bedges (13.3 MB). bedges live A->B only;
    //              convb born in pass C. Never simultaneously live.
    //   sub_edges: 16.1 MB  (live: B -> C; disjoint from convb)
    //   w1t/w2t, bcur+scur2
    char* ws = (char*)d_ws;
    unsigned short* Xb    = (unsigned short*)ws;  ws += (size_t)nNodes * DFEAT * 2;
    unsigned short* convb = (unsigned short*)ws;
    unsigned* bedges      = (unsigned*)convb;     // alias (see above)
    ws += (size_t)nNodes * DFEAT * 2;             // 25.6 MB covers bedges' 13.3 MB
    unsigned* sub_edges = (unsigned*)ws;          ws += (size_t)NSB * SUBCAP * 4;
    unsigned short* w1t = (unsigned short*)ws;    ws += 16384 * 2;
    unsigned short* w2t = (unsigned short*)ws;    ws += 16384 * 2;
    int* bcur  = (int*)ws;                        ws += 64 * 4;
    int* scur2 = (int*)ws;

    // 0) precision prep
    int n8 = nNodes * DFEAT / 8;
    x2bf_kernel<<<(n8 + 255) / 256, 256, 0, stream>>>((const float4*)X, (uint4*)Xb, n8);
    wprep<<<128, 256, 0, stream>>>(w1, w2, w1t, w2t);

    // 1) two-level edge partition (no global CSR)
    hipMemsetAsync(bcur, 0, (64 + NSB) * 4, stream);   // bcur + scur2
    int pBlocks = (nE + CHUNK - 1) / CHUNK;
    partition_edges<<<pBlocks, 256, 0, stream>>>(refA, refB, bcur, bedges, nE);
    partition_sub<<<(BUCKET_CAP / CHUNK + 1) * NBKT, 256, 0, stream>>>(
        bedges, bcur, scur2, sub_edges);

    // 2) fused counting-sort + pull aggregation per 64-node sub-bucket
    sort_aggregate<<<NSB, 256, 0, stream>>>(sub_edges, scur2,
                                            (const uint4*)Xb, (uint4*)convb);

    // 3+4) fused MLP via bf16 MFMA
    int mBlocks = (nNodes + TM - 1) / TM;
    mlp_fused<<<mBlocks, 256, 0, stream>>>(convb, w1t, b1, w2t, b2, out, nNodes);
}

// Round 9
// 211.332 us; speedup vs baseline: 1.1933x; 1.1933x over previous
//
#include <hip/hip_runtime.h>
#include <hip/hip_bf16.h>

#define NNODES 100000
#define DFEAT 128
#define NBKT 8
#define STRIPE 12500            // nodes per dst bucket (100000/8)
#define BUCKET_CAP 416000       // ~400000 expected + big slack
#define CHUNK 4096
#define SUBNODES 64             // nodes per sub-bucket
#define NSUB 196                // ceil(12500/64)
#define SUBCAP 2560             // mean 2041 + 11.5 sigma
#define NSB (NBKT * NSUB)       // 1568 sub-buckets

typedef short bf16x8 __attribute__((ext_vector_type(8)));
typedef float f32x4  __attribute__((ext_vector_type(4)));

__device__ __forceinline__ unsigned short f2bf(float f) {
    unsigned u = __builtin_bit_cast(unsigned, f);
    return (unsigned short)((u + 0x7fffu + ((u >> 16) & 1u)) >> 16);
}

// ---------------------------------------------------------------------------
// Fused prep: [0, n8b)   X fp32 -> bf16
//             [n8b, +128) W1/W2 transpose+cast
//             last block  zero bcur + scur2
// ---------------------------------------------------------------------------
__global__ __launch_bounds__(256)
void prep_all(const float4* __restrict__ X, uint4* __restrict__ Xb, int n8, int n8b,
              const float* __restrict__ w1, const float* __restrict__ w2,
              unsigned short* __restrict__ w1t, unsigned short* __restrict__ w2t,
              int* __restrict__ zbase) {
    const int bid = blockIdx.x;
    const int tid = threadIdx.x;
    if (bid < n8b) {
        int i = bid * 256 + tid;
        if (i >= n8) return;
        float4 a = X[2 * i], b = X[2 * i + 1];
        uint4 o;
        o.x = f2bf(a.x) | ((unsigned)f2bf(a.y) << 16);
        o.y = f2bf(a.z) | ((unsigned)f2bf(a.w) << 16);
        o.z = f2bf(b.x) | ((unsigned)f2bf(b.y) << 16);
        o.w = f2bf(b.z) | ((unsigned)f2bf(b.w) << 16);
        Xb[i] = o;
    } else if (bid < n8b + 128) {
        int i = (bid - n8b) * 256 + tid;          // 0..32767
        const float* w = (i < 16384) ? w1 : w2;
        unsigned short* o = (i < 16384) ? w1t : w2t;
        int j = i & 16383;
        int n = j >> 7, k = j & 127;
        o[n * 128 + k] = f2bf(w[k * 128 + n]);
    } else {
        for (int i = tid; i < 64 + NSB; i += 256) zbase[i] = 0;
    }
}

// ---------------------------------------------------------------------------
// Pass A: partition edges into 8 dst-stripe buckets (validated R5-R7).
// Entry: src | (dst - b*STRIPE)<<17. LDS reorder -> coalesced segment flush.
// ---------------------------------------------------------------------------
__global__ __launch_bounds__(256)
void partition_edges(const int* __restrict__ dst, const int* __restrict__ src,
                     int* __restrict__ bcur, unsigned* __restrict__ bedges,
                     int nE) {
    __shared__ unsigned sbuf[CHUNK];
    __shared__ int scnt[NBKT];
    __shared__ int sbase[NBKT];
    __shared__ int scur[NBKT];
    __shared__ int gbase[NBKT];

    const int tid = threadIdx.x;
    const long long e0 = (long long)blockIdx.x * CHUNK;
    const int n = (int)min((long long)CHUNK, (long long)nE - e0);
    if (n <= 0) return;

    if (tid < NBKT) scnt[tid] = 0;
    __syncthreads();

    unsigned ent[CHUNK / 256];
    int bkt[CHUNK / 256];
#pragma unroll
    for (int j = 0; j < CHUNK / 256; ++j) {
        int i = tid + j * 256;                    // coalesced
        if (i < n) {
            int d = dst[e0 + i];
            int s = src[e0 + i];
            int b = d / STRIPE;                   // 0..7 (const divisor)
            ent[j] = (unsigned)s | ((unsigned)(d - b * STRIPE) << 17);
            bkt[j] = b;
            atomicAdd(&scnt[b], 1);
        } else bkt[j] = -1;
    }
    __syncthreads();

    if (tid == 0) {
        int run = 0;
        for (int b = 0; b < NBKT; ++b) { sbase[b] = run; scur[b] = run; run += scnt[b]; }
    }
    __syncthreads();

#pragma unroll
    for (int j = 0; j < CHUNK / 256; ++j)
        if (bkt[j] >= 0) {
            int p = atomicAdd(&scur[bkt[j]], 1);
            sbuf[p] = ent[j];
        }
    if (tid < NBKT) gbase[tid] = atomicAdd(&bcur[tid], scnt[tid]);
    __syncthreads();

    for (int i = tid; i < n; i += 256) {
        int b = 0;
        while (b < NBKT - 1 && i >= sbase[b + 1]) ++b;
        bedges[(size_t)b * BUCKET_CAP + gbase[b] + (i - sbase[b])] = sbuf[i];
    }
}

// ---------------------------------------------------------------------------
// Pass B: split each bucket into 196 sub-buckets of 64 nodes (key dst_local>>6).
// Flush parallelized across the 4 waves (R7 ran 196 segments serially over
// the whole block -> this was the R7 regression).
// ---------------------------------------------------------------------------
__global__ __launch_bounds__(256)
void partition_sub(const unsigned* __restrict__ bedges, const int* __restrict__ bcur,
                   int* __restrict__ scur2, unsigned* __restrict__ sub_edges) {
    __shared__ unsigned sbuf[CHUNK];
    __shared__ int scnt[NSUB];
    __shared__ int sbase[NSUB + 1];
    __shared__ int scur[NSUB];
    __shared__ int gbase[NSUB];

    const int b   = blockIdx.x & (NBKT - 1);
    const int blk = blockIdx.x >> 3;
    const int sz  = bcur[b];
    const int e0  = blk * CHUNK;
    if (e0 >= sz) return;
    const int n = min(CHUNK, sz - e0);
    const unsigned* p = bedges + (size_t)b * BUCKET_CAP + e0;
    const int tid = threadIdx.x;

    for (int i = tid; i < NSUB; i += 256) scnt[i] = 0;
    __syncthreads();

    unsigned ent[CHUNK / 256];
    int sbk[CHUNK / 256];
#pragma unroll
    for (int j = 0; j < CHUNK / 256; ++j) {
        int i = tid + j * 256;
        if (i < n) {
            unsigned v = p[i];
            int s = (int)(v >> 23);               // dst_local>>6, 0..195
            ent[j] = v;
            sbk[j] = s;
            atomicAdd(&scnt[s], 1);
        } else sbk[j] = -1;
    }
    __syncthreads();

    if (tid == 0) {
        int run = 0;
        for (int s = 0; s < NSUB; ++s) { sbase[s] = run; scur[s] = run; run += scnt[s]; }
        sbase[NSUB] = run;
    }
    __syncthreads();

#pragma unroll
    for (int j = 0; j < CHUNK / 256; ++j)
        if (sbk[j] >= 0) {
            int pos = atomicAdd(&scur[sbk[j]], 1);
            sbuf[pos] = ent[j];
        }
    if (tid < NSUB) gbase[tid] = atomicAdd(&scur2[b * NSUB + tid], scnt[tid]);
    __syncthreads();

    // wave-parallel segment flush: wave w -> segments w, w+4, ...
    const int wave = tid >> 6, lane = tid & 63;
    for (int s = wave; s < NSUB; s += 4) {
        int lo = sbase[s], hi = sbase[s + 1];
        if (lo == hi) continue;
        int g0 = gbase[s];
        unsigned* q = sub_edges + (size_t)(b * NSUB + s) * SUBCAP;
        for (int i = lo + lane; i < hi; i += 64) {
            int o = g0 + (i - lo);
            if (o < SUBCAP) q[o] = sbuf[i];       // statistical overflow guard
        }
    }
}

// ---------------------------------------------------------------------------
// Pass C: fused counting-sort + aggregation (unchanged from R7 — measured at
// the random-gather BW ceiling ~3.2 TB/s; not the round's target).
// ---------------------------------------------------------------------------
__device__ __forceinline__ void bfadd(float* acc, uint4 v) {
    acc[0] += __builtin_bit_cast(float, v.x << 16);
    acc[1] += __builtin_bit_cast(float, v.x & 0xffff0000u);
    acc[2] += __builtin_bit_cast(float, v.y << 16);
    acc[3] += __builtin_bit_cast(float, v.y & 0xffff0000u);
    acc[4] += __builtin_bit_cast(float, v.z << 16);
    acc[5] += __builtin_bit_cast(float, v.z & 0xffff0000u);
    acc[6] += __builtin_bit_cast(float, v.w << 16);
    acc[7] += __builtin_bit_cast(float, v.w & 0xffff0000u);
}

__global__ __launch_bounds__(256, 8)
void sort_aggregate(const unsigned* __restrict__ sub_edges,
                    const int* __restrict__ scur2,
                    const uint4* __restrict__ Xb, uint4* __restrict__ convb) {
    __shared__ unsigned srt[SUBCAP];
    __shared__ int cnt[SUBNODES];
    __shared__ int off[SUBNODES + 1];
    __shared__ int cur[SUBNODES];

    const int b  = blockIdx.x & (NBKT - 1);      // reader XCD == writer XCD
    const int j  = blockIdx.x >> 3;              // 0..195
    const int sb = b * NSUB + j;
    const int tid = threadIdx.x;
    const int sz = min(scur2[sb], SUBCAP);
    const int nodeBase = b * STRIPE + j * SUBNODES;
    const int nLoc = min(SUBNODES, STRIPE - j * SUBNODES);  // 64 (last: 20)
    const unsigned* p = sub_edges + (size_t)sb * SUBCAP;

    if (tid < SUBNODES) cnt[tid] = 0;
    __syncthreads();
    for (int i = tid; i < sz; i += 256)
        atomicAdd(&cnt[(p[i] >> 17) & 63], 1);
    __syncthreads();

    // single-wave shuffle scan over 64 bins
    if (tid < 64) {
        int v = cnt[tid];
        int s = v;
#pragma unroll
        for (int d = 1; d < 64; d <<= 1) {
            int t = __shfl_up(s, d, 64);
            if (tid >= d) s += t;
        }
        off[tid + 1] = s;        // inclusive
        cur[tid] = s - v;        // exclusive
        if (tid == 0) off[0] = 0;
    }
    __syncthreads();

    // scatter into sorted order (LDS only)
    for (int i = tid; i < sz; i += 256) {
        unsigned v = p[i];
        int pos = atomicAdd(&cur[(v >> 17) & 63], 1);
        srt[pos] = v & 0x1FFFFu;
    }
    __syncthreads();

    // aggregate: 16 groups x 16 lanes; group g handles nodes g, g+16, ...
    const int grp = tid >> 4, lane = tid & 15;
    for (int n0 = grp; n0 < nLoc; n0 += 16) {
        int node = nodeBase + n0;
        float acc[8];
#pragma unroll
        for (int q = 0; q < 8; ++q) acc[q] = 0.f;
        bfadd(acc, Xb[(size_t)node * 16 + lane]);    // self term (eps=0)

        int e = off[n0], end = off[n0 + 1];
        for (; e + 4 <= end; e += 4) {
            int s0 = srt[e + 0], s1 = srt[e + 1], s2 = srt[e + 2], s3 = srt[e + 3];
            uint4 v0 = Xb[(size_t)s0 * 16 + lane];
            uint4 v1 = Xb[(size_t)s1 * 16 + lane];
            uint4 v2 = Xb[(size_t)s2 * 16 + lane];
            uint4 v3 = Xb[(size_t)s3 * 16 + lane];
            bfadd(acc, v0); bfadd(acc, v1); bfadd(acc, v2); bfadd(acc, v3);
        }
        for (; e < end; ++e)
            bfadd(acc, Xb[(size_t)srt[e] * 16 + lane]);

        uint4 o;
        o.x = f2bf(acc[0]) | ((unsigned)f2bf(acc[1]) << 16);
        o.y = f2bf(acc[2]) | ((unsigned)f2bf(acc[3]) << 16);
        o.z = f2bf(acc[4]) | ((unsigned)f2bf(acc[5]) << 16);
        o.w = f2bf(acc[6]) | ((unsigned)f2bf(acc[7]) << 16);
        convb[(size_t)node * 16 + lane] = o;
    }
}

// ---------------------------------------------------------------------------
// Fused MLP via bf16 MFMA. R8: H written in place into sA (each wave touches
// only its own 32 rows for both A-frags and C/D rows -> no cross-wave hazard),
// sH deleted: LDS 104 -> 69.6 KB -> 2 blocks/CU (was 1). launch_bounds(256,2).
// ---------------------------------------------------------------------------
#define TM 128

__global__ __launch_bounds__(256, 2)
void mlp_fused(const unsigned short* __restrict__ convb,
               const unsigned short* __restrict__ w1t, const float* __restrict__ b1,
               const unsigned short* __restrict__ w2t, const float* __restrict__ b2,
               float* __restrict__ out, int N) {
    __shared__ unsigned short sA[TM][136];
    __shared__ unsigned short sW[128][136];

    const int tid  = threadIdx.x;
    const int row0 = blockIdx.x * TM;

    for (int i = tid; i < TM * 16; i += 256) {
        int r = i >> 4, c = i & 15;
        uint4 v = make_uint4(0, 0, 0, 0);
        if (row0 + r < N) v = ((const uint4*)convb)[(size_t)(row0 + r) * 16 + c];
        *(uint4*)&sA[r][c * 8] = v;
    }
    for (int i = tid; i < 128 * 16; i += 256) {
        int r = i >> 4, c = i & 15;
        *(uint4*)&sW[r][c * 8] = ((const uint4*)w1t)[r * 16 + c];
    }
    __syncthreads();

    const int lane = tid & 63;
    const int lrow = lane & 15;
    const int kgrp = lane >> 4;
    const int m0   = (tid >> 6) * 32;

    float bias[8];
#pragma unroll
    for (int nf = 0; nf < 8; ++nf) bias[nf] = b1[nf * 16 + lrow];

    f32x4 acc[2][8] = {};
#pragma unroll
    for (int kk = 0; kk < 128; kk += 32) {
        bf16x8 a0 = *(const bf16x8*)&sA[m0 + lrow][kk + kgrp * 8];
        bf16x8 a1 = *(const bf16x8*)&sA[m0 + 16 + lrow][kk + kgrp * 8];
#pragma unroll
        for (int nf = 0; nf < 8; ++nf) {
            bf16x8 b = *(const bf16x8*)&sW[nf * 16 + lrow][kk + kgrp * 8];
            acc[0][nf] = __builtin_amdgcn_mfma_f32_16x16x32_bf16(a0, b, acc[0][nf], 0, 0, 0);
            acc[1][nf] = __builtin_amdgcn_mfma_f32_16x16x32_bf16(a1, b, acc[1][nf], 0, 0, 0);
        }
    }

    // layer-1 epilogue: relu -> bf16 -> back into sA (own rows only)
#pragma unroll
    for (int mf = 0; mf < 2; ++mf)
#pragma unroll
        for (int nf = 0; nf < 8; ++nf)
#pragma unroll
            for (int r = 0; r < 4; ++r) {
                int row = m0 + mf * 16 + kgrp * 4 + r;
                int col = nf * 16 + lrow;
                float h = fmaxf(acc[mf][nf][r] + bias[nf], 0.f);
                sA[row][col] = f2bf(h);
            }

    __syncthreads();   // all waves past MFMA1 reads of sW; sA(H) complete

    // reload sW <- W2^T
    for (int i = tid; i < 128 * 16; i += 256) {
        int r = i >> 4, c = i & 15;
        *(uint4*)&sW[r][c * 8] = ((const uint4*)w2t)[r * 16 + c];
    }
#pragma unroll
    for (int nf = 0; nf < 8; ++nf) bias[nf] = b2[nf * 16 + lrow];
#pragma unroll
    for (int mf = 0; mf < 2; ++mf)
#pragma unroll
        for (int nf = 0; nf < 8; ++nf) acc[mf][nf] = (f32x4){0.f, 0.f, 0.f, 0.f};
    __syncthreads();

#pragma unroll
    for (int kk = 0; kk < 128; kk += 32) {
        bf16x8 a0 = *(const bf16x8*)&sA[m0 + lrow][kk + kgrp * 8];
        bf16x8 a1 = *(const bf16x8*)&sA[m0 + 16 + lrow][kk + kgrp * 8];
#pragma unroll
        for (int nf = 0; nf < 8; ++nf) {
            bf16x8 b = *(const bf16x8*)&sW[nf * 16 + lrow][kk + kgrp * 8];
            acc[0][nf] = __builtin_amdgcn_mfma_f32_16x16x32_bf16(a0, b, acc[0][nf], 0, 0, 0);
            acc[1][nf] = __builtin_amdgcn_mfma_f32_16x16x32_bf16(a1, b, acc[1][nf], 0, 0, 0);
        }
    }

    // layer-2 epilogue: relu -> fp32 global
#pragma unroll
    for (int mf = 0; mf < 2; ++mf)
#pragma unroll
        for (int nf = 0; nf < 8; ++nf)
#pragma unroll
            for (int r = 0; r < 4; ++r) {
                int row = row0 + m0 + mf * 16 + kgrp * 4 + r;
                int col = nf * 16 + lrow;
                if (row < N)
                    out[(size_t)row * 128 + col] = fmaxf(acc[mf][nf][r] + bias[nf], 0.f);
            }
}

// ---------------------------------------------------------------------------
extern "C" void kernel_launch(void* const* d_in, const int* in_sizes, int n_in,
                              void* d_out, int out_size, void* d_ws, size_t ws_size,
                              hipStream_t stream) {
    const float* X    = (const float*)d_in[0];
    const int*   refA = (const int*)d_in[1];   // dst per edge
    const int*   refB = (const int*)d_in[2];   // src per edge
    const float* w1   = (const float*)d_in[3];
    const float* b1   = (const float*)d_in[4];
    const float* w2   = (const float*)d_in[5];
    const float* b2   = (const float*)d_in[6];
    float* out = (float*)d_out;

    const int nNodes = in_sizes[0] / DFEAT;    // 100000
    const int nE     = in_sizes[1];            // 3200000

    // Workspace layout with liveness-based aliasing:
    //   Xb       : 25.6 MB  (live: prep -> sort_aggregate)
    //   convb    : 25.6 MB  -- ALIASES bedges (13.3 MB). bedges live A->B only;
    //              convb born in pass C. Never simultaneously live.
    //   sub_edges: 16.1 MB  (live: B -> C; disjoint from convb)
    //   w1t/w2t, bcur+scur2 (zeroed inside prep_all)
    char* ws = (char*)d_ws;
    unsigned short* Xb    = (unsigned short*)ws;  ws += (size_t)nNodes * DFEAT * 2;
    unsigned short* convb = (unsigned short*)ws;
    unsigned* bedges      = (unsigned*)convb;     // alias (see above)
    ws += (size_t)nNodes * DFEAT * 2;             // 25.6 MB covers bedges' 13.3 MB
    unsigned* sub_edges = (unsigned*)ws;          ws += (size_t)NSB * SUBCAP * 4;
    unsigned short* w1t = (unsigned short*)ws;    ws += 16384 * 2;
    unsigned short* w2t = (unsigned short*)ws;    ws += 16384 * 2;
    int* bcur  = (int*)ws;                        ws += 64 * 4;
    int* scur2 = (int*)ws;

    // 0) fused prep: x2bf + wprep + zero(bcur,scur2)
    int n8  = nNodes * DFEAT / 8;
    int n8b = (n8 + 255) / 256;
    prep_all<<<n8b + 128 + 1, 256, 0, stream>>>((const float4*)X, (uint4*)Xb, n8, n8b,
                                                w1, w2, w1t, w2t, bcur);

    // 1) two-level edge partition (no global CSR)
    int pBlocks = (nE + CHUNK - 1) / CHUNK;
    partition_edges<<<pBlocks, 256, 0, stream>>>(refA, refB, bcur, bedges, nE);
    partition_sub<<<(BUCKET_CAP / CHUNK + 1) * NBKT, 256, 0, stream>>>(
        bedges, bcur, scur2, sub_edges);

    // 2) fused counting-sort + pull aggregation per 64-node sub-bucket
    sort_aggregate<<<NSB, 256, 0, stream>>>(sub_edges, scur2,
                                            (const uint4*)Xb, (uint4*)convb);

    // 3+4) fused MLP via bf16 MFMA
    int mBlocks = (nNodes + TM - 1) / TM;
    mlp_fused<<<mBlocks, 256, 0, stream>>>(convb, w1t, b1, w2t, b2, out, nNodes);
}

// Round 10
// 210.542 us; speedup vs baseline: 1.1978x; 1.0038x over previous
//
#include <hip/hip_runtime.h>
#include <hip/hip_bf16.h>

#define NNODES 100000
#define DFEAT 128
#define NBKT 8
#define STRIPE 12500            // nodes per dst bucket (100000/8)
#define BUCKET_CAP 416000       // ~400000 expected + big slack
#define CHUNK 4096
#define SUBNODES 64             // nodes per sub-bucket
#define NSUB 196                // ceil(12500/64)
#define SUBCAP 2560             // mean 2041 + 11.5 sigma
#define NSB (NBKT * NSUB)       // 1568 sub-buckets
#define NBIN (SUBNODES * 16)    // sort bins: (node<<4) | src_slab, slab=src>>13

typedef short bf16x8 __attribute__((ext_vector_type(8)));
typedef float f32x4  __attribute__((ext_vector_type(4)));

__device__ __forceinline__ unsigned short f2bf(float f) {
    unsigned u = __builtin_bit_cast(unsigned, f);
    return (unsigned short)((u + 0x7fffu + ((u >> 16) & 1u)) >> 16);
}

// ---------------------------------------------------------------------------
// Fused prep: [0, n8b)   X fp32 -> bf16
//             [n8b, +128) W1/W2 transpose+cast
//             last block  zero bcur + scur2
// ---------------------------------------------------------------------------
__global__ __launch_bounds__(256)
void prep_all(const float4* __restrict__ X, uint4* __restrict__ Xb, int n8, int n8b,
              const float* __restrict__ w1, const float* __restrict__ w2,
              unsigned short* __restrict__ w1t, unsigned short* __restrict__ w2t,
              int* __restrict__ zbase) {
    const int bid = blockIdx.x;
    const int tid = threadIdx.x;
    if (bid < n8b) {
        int i = bid * 256 + tid;
        if (i >= n8) return;
        float4 a = X[2 * i], b = X[2 * i + 1];
        uint4 o;
        o.x = f2bf(a.x) | ((unsigned)f2bf(a.y) << 16);
        o.y = f2bf(a.z) | ((unsigned)f2bf(a.w) << 16);
        o.z = f2bf(b.x) | ((unsigned)f2bf(b.y) << 16);
        o.w = f2bf(b.z) | ((unsigned)f2bf(b.w) << 16);
        Xb[i] = o;
    } else if (bid < n8b + 128) {
        int i = (bid - n8b) * 256 + tid;          // 0..32767
        const float* w = (i < 16384) ? w1 : w2;
        unsigned short* o = (i < 16384) ? w1t : w2t;
        int j = i & 16383;
        int n = j >> 7, k = j & 127;
        o[n * 128 + k] = f2bf(w[k * 128 + n]);
    } else {
        for (int i = tid; i < 64 + NSB; i += 256) zbase[i] = 0;
    }
}

// ---------------------------------------------------------------------------
// Pass A: partition edges into 8 dst-stripe buckets (validated R5-R8).
// Entry: src | (dst - b*STRIPE)<<17. LDS reorder -> coalesced segment flush.
// ---------------------------------------------------------------------------
__global__ __launch_bounds__(256)
void partition_edges(const int* __restrict__ dst, const int* __restrict__ src,
                     int* __restrict__ bcur, unsigned* __restrict__ bedges,
                     int nE) {
    __shared__ unsigned sbuf[CHUNK];
    __shared__ int scnt[NBKT];
    __shared__ int sbase[NBKT];
    __shared__ int scur[NBKT];
    __shared__ int gbase[NBKT];

    const int tid = threadIdx.x;
    const long long e0 = (long long)blockIdx.x * CHUNK;
    const int n = (int)min((long long)CHUNK, (long long)nE - e0);
    if (n <= 0) return;

    if (tid < NBKT) scnt[tid] = 0;
    __syncthreads();

    unsigned ent[CHUNK / 256];
    int bkt[CHUNK / 256];
#pragma unroll
    for (int j = 0; j < CHUNK / 256; ++j) {
        int i = tid + j * 256;                    // coalesced
        if (i < n) {
            int d = dst[e0 + i];
            int s = src[e0 + i];
            int b = d / STRIPE;                   // 0..7 (const divisor)
            ent[j] = (unsigned)s | ((unsigned)(d - b * STRIPE) << 17);
            bkt[j] = b;
            atomicAdd(&scnt[b], 1);
        } else bkt[j] = -1;
    }
    __syncthreads();

    if (tid == 0) {
        int run = 0;
        for (int b = 0; b < NBKT; ++b) { sbase[b] = run; scur[b] = run; run += scnt[b]; }
    }
    __syncthreads();

#pragma unroll
    for (int j = 0; j < CHUNK / 256; ++j)
        if (bkt[j] >= 0) {
            int p = atomicAdd(&scur[bkt[j]], 1);
            sbuf[p] = ent[j];
        }
    if (tid < NBKT) gbase[tid] = atomicAdd(&bcur[tid], scnt[tid]);
    __syncthreads();

    for (int i = tid; i < n; i += 256) {
        int b = 0;
        while (b < NBKT - 1 && i >= sbase[b + 1]) ++b;
        bedges[(size_t)b * BUCKET_CAP + gbase[b] + (i - sbase[b])] = sbuf[i];
    }
}

// ---------------------------------------------------------------------------
// Pass B: split each bucket into 196 sub-buckets of 64 nodes (key dst_local>>6).
// Wave-parallel segment flush (R8 fix).
// ---------------------------------------------------------------------------
__global__ __launch_bounds__(256)
void partition_sub(const unsigned* __restrict__ bedges, const int* __restrict__ bcur,
                   int* __restrict__ scur2, unsigned* __restrict__ sub_edges) {
    __shared__ unsigned sbuf[CHUNK];
    __shared__ int scnt[NSUB];
    __shared__ int sbase[NSUB + 1];
    __shared__ int scur[NSUB];
    __shared__ int gbase[NSUB];

    const int b   = blockIdx.x & (NBKT - 1);
    const int blk = blockIdx.x >> 3;
    const int sz  = bcur[b];
    const int e0  = blk * CHUNK;
    if (e0 >= sz) return;
    const int n = min(CHUNK, sz - e0);
    const unsigned* p = bedges + (size_t)b * BUCKET_CAP + e0;
    const int tid = threadIdx.x;

    for (int i = tid; i < NSUB; i += 256) scnt[i] = 0;
    __syncthreads();

    unsigned ent[CHUNK / 256];
    int sbk[CHUNK / 256];
#pragma unroll
    for (int j = 0; j < CHUNK / 256; ++j) {
        int i = tid + j * 256;
        if (i < n) {
            unsigned v = p[i];
            int s = (int)(v >> 23);               // dst_local>>6, 0..195
            ent[j] = v;
            sbk[j] = s;
            atomicAdd(&scnt[s], 1);
        } else sbk[j] = -1;
    }
    __syncthreads();

    if (tid == 0) {
        int run = 0;
        for (int s = 0; s < NSUB; ++s) { sbase[s] = run; scur[s] = run; run += scnt[s]; }
        sbase[NSUB] = run;
    }
    __syncthreads();

#pragma unroll
    for (int j = 0; j < CHUNK / 256; ++j)
        if (sbk[j] >= 0) {
            int pos = atomicAdd(&scur[sbk[j]], 1);
            sbuf[pos] = ent[j];
        }
    if (tid < NSUB) gbase[tid] = atomicAdd(&scur2[b * NSUB + tid], scnt[tid]);
    __syncthreads();

    // wave-parallel segment flush: wave w -> segments w, w+4, ...
    const int wave = tid >> 6, lane = tid & 63;
    for (int s = wave; s < NSUB; s += 4) {
        int lo = sbase[s], hi = sbase[s + 1];
        if (lo == hi) continue;
        int g0 = gbase[s];
        unsigned* q = sub_edges + (size_t)(b * NSUB + s) * SUBCAP;
        for (int i = lo + lane; i < hi; i += 64) {
            int o = g0 + (i - lo);
            if (o < SUBCAP) q[o] = sbuf[i];       // statistical overflow guard
        }
    }
}

// ---------------------------------------------------------------------------
// Pass C: fused counting-sort + aggregation. R9 change: sort key widened to
// (node_local<<4) | src_slab (slab = src>>13, 13 slabs x 8192 nodes = 2MB of
// Xb each). Per-node segments stay contiguous (off at node granularity), but
// edges within a node come out slab-ordered -> all lane groups and (loosely)
// all co-resident blocks sweep Xb slab-by-slab instead of uniformly at
// random -> per-XCD L2 working set ~2-4MB instead of 25.6MB. Targets the 43%
// L2 hit rate (FETCH 355MB vs 819MB logical) seen in R7/R8.
// ---------------------------------------------------------------------------
__device__ __forceinline__ void bfadd(float* acc, uint4 v) {
    acc[0] += __builtin_bit_cast(float, v.x << 16);
    acc[1] += __builtin_bit_cast(float, v.x & 0xffff0000u);
    acc[2] += __builtin_bit_cast(float, v.y << 16);
    acc[3] += __builtin_bit_cast(float, v.y & 0xffff0000u);
    acc[4] += __builtin_bit_cast(float, v.z << 16);
    acc[5] += __builtin_bit_cast(float, v.z & 0xffff0000u);
    acc[6] += __builtin_bit_cast(float, v.w << 16);
    acc[7] += __builtin_bit_cast(float, v.w & 0xffff0000u);
}

__global__ __launch_bounds__(256, 8)
void sort_aggregate(const unsigned* __restrict__ sub_edges,
                    const int* __restrict__ scur2,
                    const uint4* __restrict__ Xb, uint4* __restrict__ convb) {
    __shared__ unsigned srt[SUBCAP];
    __shared__ int cnt[NBIN];          // re-used as cursor after scan
    __shared__ int off[NBIN + 1];
    __shared__ int tmp[256];

    const int b  = blockIdx.x & (NBKT - 1);      // reader XCD == writer XCD
    const int j  = blockIdx.x >> 3;              // 0..195
    const int sb = b * NSUB + j;
    const int tid = threadIdx.x;
    const int sz = min(scur2[sb], SUBCAP);
    const int nodeBase = b * STRIPE + j * SUBNODES;
    const int nLoc = min(SUBNODES, STRIPE - j * SUBNODES);  // 64 (last: 20)
    const unsigned* p = sub_edges + (size_t)sb * SUBCAP;

#pragma unroll
    for (int q = 0; q < 4; ++q) cnt[tid * 4 + q] = 0;
    __syncthreads();
    for (int i = tid; i < sz; i += 256) {
        unsigned v = p[i];
        int key = (int)(((v >> 17) & 63) << 4) | (int)((v & 0x1FFFFu) >> 13);
        atomicAdd(&cnt[key], 1);
    }
    __syncthreads();

    // scan 1024 bins: 4/thread serial + Hillis-Steele over 256 partials
    int c0 = cnt[tid * 4], c1 = cnt[tid * 4 + 1],
        c2 = cnt[tid * 4 + 2], c3 = cnt[tid * 4 + 3];
    int tot = c0 + c1 + c2 + c3;
    tmp[tid] = tot;
    __syncthreads();
    for (int d = 1; d < 256; d <<= 1) {
        int t = (tid >= d) ? tmp[tid - d] : 0;
        __syncthreads();
        tmp[tid] += t;
        __syncthreads();
    }
    int base = tmp[tid] - tot;                   // exclusive
    off[tid * 4 + 0] = base;
    off[tid * 4 + 1] = base + c0;
    off[tid * 4 + 2] = base + c0 + c1;
    off[tid * 4 + 3] = base + c0 + c1 + c2;
    if (tid == 255) off[NBIN] = tmp[255];
    __syncthreads();
#pragma unroll
    for (int q = 0; q < 4; ++q) cnt[tid * 4 + q] = off[tid * 4 + q];  // cursors
    __syncthreads();

    // scatter into (node, slab)-sorted order (LDS only)
    for (int i = tid; i < sz; i += 256) {
        unsigned v = p[i];
        unsigned s = v & 0x1FFFFu;
        int key = (int)(((v >> 17) & 63) << 4) | (int)(s >> 13);
        int pos = atomicAdd(&cnt[key], 1);
        srt[pos] = s;
    }
    __syncthreads();

    // aggregate: 16 groups x 16 lanes; group g handles nodes g, g+16, ...
    // per-node segment = [off[n<<4], off[(n+1)<<4]) -- contiguous, slab-ordered
    const int grp = tid >> 4, lane = tid & 15;
    for (int n0 = grp; n0 < nLoc; n0 += 16) {
        int node = nodeBase + n0;
        float acc[8];
#pragma unroll
        for (int q = 0; q < 8; ++q) acc[q] = 0.f;
        bfadd(acc, Xb[(size_t)node * 16 + lane]);    // self term (eps=0)

        int e = off[n0 << 4], end = off[(n0 + 1) << 4];
        for (; e + 4 <= end; e += 4) {
            int s0 = srt[e + 0], s1 = srt[e + 1], s2 = srt[e + 2], s3 = srt[e + 3];
            uint4 v0 = Xb[(size_t)s0 * 16 + lane];
            uint4 v1 = Xb[(size_t)s1 * 16 + lane];
            uint4 v2 = Xb[(size_t)s2 * 16 + lane];
            uint4 v3 = Xb[(size_t)s3 * 16 + lane];
            bfadd(acc, v0); bfadd(acc, v1); bfadd(acc, v2); bfadd(acc, v3);
        }
        for (; e < end; ++e)
            bfadd(acc, Xb[(size_t)srt[e] * 16 + lane]);

        uint4 o;
        o.x = f2bf(acc[0]) | ((unsigned)f2bf(acc[1]) << 16);
        o.y = f2bf(acc[2]) | ((unsigned)f2bf(acc[3]) << 16);
        o.z = f2bf(acc[4]) | ((unsigned)f2bf(acc[5]) << 16);
        o.w = f2bf(acc[6]) | ((unsigned)f2bf(acc[7]) << 16);
        convb[(size_t)node * 16 + lane] = o;
    }
}

// ---------------------------------------------------------------------------
// Fused MLP via bf16 MFMA (validated R4-R8; H in place in sA, 2 blocks/CU)
// ---------------------------------------------------------------------------
#define TM 128

__global__ __launch_bounds__(256, 2)
void mlp_fused(const unsigned short* __restrict__ convb,
               const unsigned short* __restrict__ w1t, const float* __restrict__ b1,
               const unsigned short* __restrict__ w2t, const float* __restrict__ b2,
               float* __restrict__ out, int N) {
    __shared__ unsigned short sA[TM][136];
    __shared__ unsigned short sW[128][136];

    const int tid  = threadIdx.x;
    const int row0 = blockIdx.x * TM;

    for (int i = tid; i < TM * 16; i += 256) {
        int r = i >> 4, c = i & 15;
        uint4 v = make_uint4(0, 0, 0, 0);
        if (row0 + r < N) v = ((const uint4*)convb)[(size_t)(row0 + r) * 16 + c];
        *(uint4*)&sA[r][c * 8] = v;
    }
    for (int i = tid; i < 128 * 16; i += 256) {
        int r = i >> 4, c = i & 15;
        *(uint4*)&sW[r][c * 8] = ((const uint4*)w1t)[r * 16 + c];
    }
    __syncthreads();

    const int lane = tid & 63;
    const int lrow = lane & 15;
    const int kgrp = lane >> 4;
    const int m0   = (tid >> 6) * 32;

    float bias[8];
#pragma unroll
    for (int nf = 0; nf < 8; ++nf) bias[nf] = b1[nf * 16 + lrow];

    f32x4 acc[2][8] = {};
#pragma unroll
    for (int kk = 0; kk < 128; kk += 32) {
        bf16x8 a0 = *(const bf16x8*)&sA[m0 + lrow][kk + kgrp * 8];
        bf16x8 a1 = *(const bf16x8*)&sA[m0 + 16 + lrow][kk + kgrp * 8];
#pragma unroll
        for (int nf = 0; nf < 8; ++nf) {
            bf16x8 b = *(const bf16x8*)&sW[nf * 16 + lrow][kk + kgrp * 8];
            acc[0][nf] = __builtin_amdgcn_mfma_f32_16x16x32_bf16(a0, b, acc[0][nf], 0, 0, 0);
            acc[1][nf] = __builtin_amdgcn_mfma_f32_16x16x32_bf16(a1, b, acc[1][nf], 0, 0, 0);
        }
    }

    // layer-1 epilogue: relu -> bf16 -> back into sA (own rows only)
#pragma unroll
    for (int mf = 0; mf < 2; ++mf)
#pragma unroll
        for (int nf = 0; nf < 8; ++nf)
#pragma unroll
            for (int r = 0; r < 4; ++r) {
                int row = m0 + mf * 16 + kgrp * 4 + r;
                int col = nf * 16 + lrow;
                float h = fmaxf(acc[mf][nf][r] + bias[nf], 0.f);
                sA[row][col] = f2bf(h);
            }

    __syncthreads();   // all waves past MFMA1 reads of sW; sA(H) complete

    // reload sW <- W2^T
    for (int i = tid; i < 128 * 16; i += 256) {
        int r = i >> 4, c = i & 15;
        *(uint4*)&sW[r][c * 8] = ((const uint4*)w2t)[r * 16 + c];
    }
#pragma unroll
    for (int nf = 0; nf < 8; ++nf) bias[nf] = b2[nf * 16 + lrow];
#pragma unroll
    for (int mf = 0; mf < 2; ++mf)
#pragma unroll
        for (int nf = 0; nf < 8; ++nf) acc[mf][nf] = (f32x4){0.f, 0.f, 0.f, 0.f};
    __syncthreads();

#pragma unroll
    for (int kk = 0; kk < 128; kk += 32) {
        bf16x8 a0 = *(const bf16x8*)&sA[m0 + lrow][kk + kgrp * 8];
        bf16x8 a1 = *(const bf16x8*)&sA[m0 + 16 + lrow][kk + kgrp * 8];
#pragma unroll
        for (int nf = 0; nf < 8; ++nf) {
            bf16x8 b = *(const bf16x8*)&sW[nf * 16 + lrow][kk + kgrp * 8];
            acc[0][nf] = __builtin_amdgcn_mfma_f32_16x16x32_bf16(a0, b, acc[0][nf], 0, 0, 0);
            acc[1][nf] = __builtin_amdgcn_mfma_f32_16x16x32_bf16(a1, b, acc[1][nf], 0, 0, 0);
        }
    }

    // layer-2 epilogue: relu -> fp32 global
#pragma unroll
    for (int mf = 0; mf < 2; ++mf)
#pragma unroll
        for (int nf = 0; nf < 8; ++nf)
#pragma unroll
            for (int r = 0; r < 4; ++r) {
                int row = row0 + m0 + mf * 16 + kgrp * 4 + r;
                int col = nf * 16 + lrow;
                if (row < N)
                    out[(size_t)row * 128 + col] = fmaxf(acc[mf][nf][r] + bias[nf], 0.f);
            }
}

// ---------------------------------------------------------------------------
extern "C" void kernel_launch(void* const* d_in, const int* in_sizes, int n_in,
                              void* d_out, int out_size, void* d_ws, size_t ws_size,
                              hipStream_t stream) {
    const float* X    = (const float*)d_in[0];
    const int*   refA = (const int*)d_in[1];   // dst per edge
    const int*   refB = (const int*)d_in[2];   // src per edge
    const float* w1   = (const float*)d_in[3];
    const float* b1   = (const float*)d_in[4];
    const float* w2   = (const float*)d_in[5];
    const float* b2   = (const float*)d_in[6];
    float* out = (float*)d_out;

    const int nNodes = in_sizes[0] / DFEAT;    // 100000
    const int nE     = in_sizes[1];            // 3200000

    // Workspace layout with liveness-based aliasing:
    //   Xb       : 25.6 MB  (live: prep -> sort_aggregate)
    //   convb    : 25.6 MB  -- ALIASES bedges (13.3 MB). bedges live A->B only;
    //              convb born in pass C. Never simultaneously live.
    //   sub_edges: 16.1 MB  (live: B -> C; disjoint from convb)
    //   w1t/w2t, bcur+scur2 (zeroed inside prep_all)
    char* ws = (char*)d_ws;
    unsigned short* Xb    = (unsigned short*)ws;  ws += (size_t)nNodes * DFEAT * 2;
    unsigned short* convb = (unsigned short*)ws;
    unsigned* bedges      = (unsigned*)convb;     // alias (see above)
    ws += (size_t)nNodes * DFEAT * 2;             // 25.6 MB covers bedges' 13.3 MB
    unsigned* sub_edges = (unsigned*)ws;          ws += (size_t)NSB * SUBCAP * 4;
    unsigned short* w1t = (unsigned short*)ws;    ws += 16384 * 2;
    unsigned short* w2t = (unsigned short*)ws;    ws += 16384 * 2;
    int* bcur  = (int*)ws;                        ws += 64 * 4;
    int* scur2 = (int*)ws;

    // 0) fused prep: x2bf + wprep + zero(bcur,scur2)
    int n8  = nNodes * DFEAT / 8;
    int n8b = (n8 + 255) / 256;
    prep_all<<<n8b + 128 + 1, 256, 0, stream>>>((const float4*)X, (uint4*)Xb, n8, n8b,
                                                w1, w2, w1t, w2t, bcur);

    // 1) two-level edge partition (no global CSR)
    int pBlocks = (nE + CHUNK - 1) / CHUNK;
    partition_edges<<<pBlocks, 256, 0, stream>>>(refA, refB, bcur, bedges, nE);
    partition_sub<<<(BUCKET_CAP / CHUNK + 1) * NBKT, 256, 0, stream>>>(
        bedges, bcur, scur2, sub_edges);

    // 2) fused counting-sort (node,src-slab) + pull aggregation
    sort_aggregate<<<NSB, 256, 0, stream>>>(sub_edges, scur2,
                                            (const uint4*)Xb, (uint4*)convb);

    // 3+4) fused MLP via bf16 MFMA
    int mBlocks = (nNodes + TM - 1) / TM;
    mlp_fused<<<mBlocks, 256, 0, stream>>>(convb, w1t, b1, w2t, b2, out, nNodes);
}

// Round 11
// 202.800 us; speedup vs baseline: 1.2435x; 1.0382x over previous
//
#include <hip/hip_runtime.h>
#include <hip/hip_bf16.h>

#define NNODES 100000
#define DFEAT 128
#define NBKT 8
#define STRIPE 12500            // nodes per dst bucket (100000/8)
#define BUCKET_CAP 416000       // ~400000 expected + big slack
#define CHUNK 4096
#define SUBNODES 64             // nodes per sub-bucket
#define NSUB 196                // ceil(12500/64)
#define SUBCAP 2560             // mean 2041 + 11.5 sigma
#define NSB (NBKT * NSUB)       // 1568 sub-buckets
#define NSLAB 13                // src slabs of 8192 nodes (2MB of Xb each)
#define NBIN (NSLAB * SUBNODES) // 832 sort bins: slab*64 + node  (SLAB-MAJOR)
#define NBINP 1024              // padded for 4-per-thread scan

typedef short bf16x8 __attribute__((ext_vector_type(8)));
typedef float f32x4  __attribute__((ext_vector_type(4)));

__device__ __forceinline__ unsigned short f2bf(float f) {
    unsigned u = __builtin_bit_cast(unsigned, f);
    return (unsigned short)((u + 0x7fffu + ((u >> 16) & 1u)) >> 16);
}

// ---------------------------------------------------------------------------
// Fused prep: [0, n8b)   X fp32 -> bf16
//             [n8b, +128) W1/W2 transpose+cast
//             last block  zero bcur + scur2
// ---------------------------------------------------------------------------
__global__ __launch_bounds__(256)
void prep_all(const float4* __restrict__ X, uint4* __restrict__ Xb, int n8, int n8b,
              const float* __restrict__ w1, const float* __restrict__ w2,
              unsigned short* __restrict__ w1t, unsigned short* __restrict__ w2t,
              int* __restrict__ zbase) {
    const int bid = blockIdx.x;
    const int tid = threadIdx.x;
    if (bid < n8b) {
        int i = bid * 256 + tid;
        if (i >= n8) return;
        float4 a = X[2 * i], b = X[2 * i + 1];
        uint4 o;
        o.x = f2bf(a.x) | ((unsigned)f2bf(a.y) << 16);
        o.y = f2bf(a.z) | ((unsigned)f2bf(a.w) << 16);
        o.z = f2bf(b.x) | ((unsigned)f2bf(b.y) << 16);
        o.w = f2bf(b.z) | ((unsigned)f2bf(b.w) << 16);
        Xb[i] = o;
    } else if (bid < n8b + 128) {
        int i = (bid - n8b) * 256 + tid;          // 0..32767
        const float* w = (i < 16384) ? w1 : w2;
        unsigned short* o = (i < 16384) ? w1t : w2t;
        int j = i & 16383;
        int n = j >> 7, k = j & 127;
        o[n * 128 + k] = f2bf(w[k * 128 + n]);
    } else {
        for (int i = tid; i < 64 + NSB; i += 256) zbase[i] = 0;
    }
}

// ---------------------------------------------------------------------------
// Pass A: partition edges into 8 dst-stripe buckets (validated R5-R9).
// ---------------------------------------------------------------------------
__global__ __launch_bounds__(256)
void partition_edges(const int* __restrict__ dst, const int* __restrict__ src,
                     int* __restrict__ bcur, unsigned* __restrict__ bedges,
                     int nE) {
    __shared__ unsigned sbuf[CHUNK];
    __shared__ int scnt[NBKT];
    __shared__ int sbase[NBKT];
    __shared__ int scur[NBKT];
    __shared__ int gbase[NBKT];

    const int tid = threadIdx.x;
    const long long e0 = (long long)blockIdx.x * CHUNK;
    const int n = (int)min((long long)CHUNK, (long long)nE - e0);
    if (n <= 0) return;

    if (tid < NBKT) scnt[tid] = 0;
    __syncthreads();

    unsigned ent[CHUNK / 256];
    int bkt[CHUNK / 256];
#pragma unroll
    for (int j = 0; j < CHUNK / 256; ++j) {
        int i = tid + j * 256;                    // coalesced
        if (i < n) {
            int d = dst[e0 + i];
            int s = src[e0 + i];
            int b = d / STRIPE;                   // 0..7 (const divisor)
            ent[j] = (unsigned)s | ((unsigned)(d - b * STRIPE) << 17);
            bkt[j] = b;
            atomicAdd(&scnt[b], 1);
        } else bkt[j] = -1;
    }
    __syncthreads();

    if (tid == 0) {
        int run = 0;
        for (int b = 0; b < NBKT; ++b) { sbase[b] = run; scur[b] = run; run += scnt[b]; }
    }
    __syncthreads();

#pragma unroll
    for (int j = 0; j < CHUNK / 256; ++j)
        if (bkt[j] >= 0) {
            int p = atomicAdd(&scur[bkt[j]], 1);
            sbuf[p] = ent[j];
        }
    if (tid < NBKT) gbase[tid] = atomicAdd(&bcur[tid], scnt[tid]);
    __syncthreads();

    for (int i = tid; i < n; i += 256) {
        int b = 0;
        while (b < NBKT - 1 && i >= sbase[b + 1]) ++b;
        bedges[(size_t)b * BUCKET_CAP + gbase[b] + (i - sbase[b])] = sbuf[i];
    }
}

// ---------------------------------------------------------------------------
// Pass B: split each bucket into 196 sub-buckets of 64 nodes (key dst_local>>6).
// Wave-parallel segment flush (R8 fix).
// ---------------------------------------------------------------------------
__global__ __launch_bounds__(256)
void partition_sub(const unsigned* __restrict__ bedges, const int* __restrict__ bcur,
                   int* __restrict__ scur2, unsigned* __restrict__ sub_edges) {
    __shared__ unsigned sbuf[CHUNK];
    __shared__ int scnt[NSUB];
    __shared__ int sbase[NSUB + 1];
    __shared__ int scur[NSUB];
    __shared__ int gbase[NSUB];

    const int b   = blockIdx.x & (NBKT - 1);
    const int blk = blockIdx.x >> 3;
    const int sz  = bcur[b];
    const int e0  = blk * CHUNK;
    if (e0 >= sz) return;
    const int n = min(CHUNK, sz - e0);
    const unsigned* p = bedges + (size_t)b * BUCKET_CAP + e0;
    const int tid = threadIdx.x;

    for (int i = tid; i < NSUB; i += 256) scnt[i] = 0;
    __syncthreads();

    unsigned ent[CHUNK / 256];
    int sbk[CHUNK / 256];
#pragma unroll
    for (int j = 0; j < CHUNK / 256; ++j) {
        int i = tid + j * 256;
        if (i < n) {
            unsigned v = p[i];
            int s = (int)(v >> 23);               // dst_local>>6, 0..195
            ent[j] = v;
            sbk[j] = s;
            atomicAdd(&scnt[s], 1);
        } else sbk[j] = -1;
    }
    __syncthreads();

    if (tid == 0) {
        int run = 0;
        for (int s = 0; s < NSUB; ++s) { sbase[s] = run; scur[s] = run; run += scnt[s]; }
        sbase[NSUB] = run;
    }
    __syncthreads();

#pragma unroll
    for (int j = 0; j < CHUNK / 256; ++j)
        if (sbk[j] >= 0) {
            int pos = atomicAdd(&scur[sbk[j]], 1);
            sbuf[pos] = ent[j];
        }
    if (tid < NSUB) gbase[tid] = atomicAdd(&scur2[b * NSUB + tid], scnt[tid]);
    __syncthreads();

    // wave-parallel segment flush: wave w -> segments w, w+4, ...
    const int wave = tid >> 6, lane = tid & 63;
    for (int s = wave; s < NSUB; s += 4) {
        int lo = sbase[s], hi = sbase[s + 1];
        if (lo == hi) continue;
        int g0 = gbase[s];
        unsigned* q = sub_edges + (size_t)(b * NSUB + s) * SUBCAP;
        for (int i = lo + lane; i < hi; i += 64) {
            int o = g0 + (i - lo);
            if (o < SUBCAP) q[o] = sbuf[i];       // statistical overflow guard
        }
    }
}

// ---------------------------------------------------------------------------
// Pass C: fused counting-sort + aggregation, SLAB-MAJOR (R10).
// Key = slab*64 + node: the block processes ALL its slab-0 edges, then slab-1,
// ... Each 16-lane group owns 4 nodes (g, g+16, g+32, g+48) with accumulators
// held in registers across all 13 slab phases; per slab it walks the 4 short
// per-(slab,node) segments in lockstep (4 independent load+add chains, ILP=4).
// All 196 blocks/XCD launch together with near-equal phase lengths -> the
// XCD's gathers concentrate in one 2MB slab at a time -> slab L2-resident.
// Fetch floor: 25.6MB/XCD = 205MB total (R9 measured 350MB).
// ---------------------------------------------------------------------------
__device__ __forceinline__ void bfadd(float* acc, uint4 v) {
    acc[0] += __builtin_bit_cast(float, v.x << 16);
    acc[1] += __builtin_bit_cast(float, v.x & 0xffff0000u);
    acc[2] += __builtin_bit_cast(float, v.y << 16);
    acc[3] += __builtin_bit_cast(float, v.y & 0xffff0000u);
    acc[4] += __builtin_bit_cast(float, v.z << 16);
    acc[5] += __builtin_bit_cast(float, v.z & 0xffff0000u);
    acc[6] += __builtin_bit_cast(float, v.w << 16);
    acc[7] += __builtin_bit_cast(float, v.w & 0xffff0000u);
}

__device__ __forceinline__ void packout(uint4* convb, int node, int lane,
                                        const float* acc) {
    uint4 o;
    o.x = f2bf(acc[0]) | ((unsigned)f2bf(acc[1]) << 16);
    o.y = f2bf(acc[2]) | ((unsigned)f2bf(acc[3]) << 16);
    o.z = f2bf(acc[4]) | ((unsigned)f2bf(acc[5]) << 16);
    o.w = f2bf(acc[6]) | ((unsigned)f2bf(acc[7]) << 16);
    convb[(size_t)node * 16 + lane] = o;
}

__global__ __launch_bounds__(256, 4)
void sort_aggregate(const unsigned* __restrict__ sub_edges,
                    const int* __restrict__ scur2,
                    const uint4* __restrict__ Xb, uint4* __restrict__ convb) {
    __shared__ unsigned srt[SUBCAP];
    __shared__ int cnt[NBINP];         // re-used as cursor after scan
    __shared__ int off[NBIN + 1];
    __shared__ int tmp[256];

    const int b  = blockIdx.x & (NBKT - 1);      // reader XCD == writer XCD
    const int j  = blockIdx.x >> 3;              // 0..195
    const int sb = b * NSUB + j;
    const int tid = threadIdx.x;
    const int sz = min(scur2[sb], SUBCAP);
    const int nodeBase = b * STRIPE + j * SUBNODES;
    const int nLoc = min(SUBNODES, STRIPE - j * SUBNODES);  // 64 (last: 20)
    const unsigned* p = sub_edges + (size_t)sb * SUBCAP;

#pragma unroll
    for (int q = 0; q < 4; ++q) cnt[tid * 4 + q] = 0;
    __syncthreads();
    for (int i = tid; i < sz; i += 256) {
        unsigned v = p[i];
        int key = (int)((v & 0x1FFFFu) >> 13) * SUBNODES + (int)((v >> 17) & 63);
        atomicAdd(&cnt[key], 1);
    }
    __syncthreads();

    // scan 1024 padded bins: 4/thread serial + Hillis-Steele over 256 partials
    int c0 = cnt[tid * 4], c1 = cnt[tid * 4 + 1],
        c2 = cnt[tid * 4 + 2], c3 = cnt[tid * 4 + 3];
    int tot = c0 + c1 + c2 + c3;
    tmp[tid] = tot;
    __syncthreads();
    for (int d = 1; d < 256; d <<= 1) {
        int t = (tid >= d) ? tmp[tid - d] : 0;
        __syncthreads();
        tmp[tid] += t;
        __syncthreads();
    }
    int base = tmp[tid] - tot;                   // exclusive
    int k = tid * 4;
    int b0 = base, b1 = base + c0, b2 = base + c0 + c1, b3 = base + c0 + c1 + c2;
    if (k     <= NBIN) off[k]     = b0;
    if (k + 1 <= NBIN) off[k + 1] = b1;
    if (k + 2 <= NBIN) off[k + 2] = b2;
    if (k + 3 <= NBIN) off[k + 3] = b3;
    __syncthreads();
    cnt[k] = b0; cnt[k + 1] = b1; cnt[k + 2] = b2; cnt[k + 3] = b3;  // cursors
    __syncthreads();

    // scatter into (slab, node)-sorted order (LDS only)
    for (int i = tid; i < sz; i += 256) {
        unsigned v = p[i];
        unsigned s = v & 0x1FFFFu;
        int key = (int)(s >> 13) * SUBNODES + (int)((v >> 17) & 63);
        int pos = atomicAdd(&cnt[key], 1);
        srt[pos] = s;
    }
    __syncthreads();

    // slab-major aggregation: group g owns nodes g, g+16, g+32, g+48
    const int grp = tid >> 4, lane = tid & 15;
    const int n0 = grp, n1 = grp + 16, n2 = grp + 32, n3 = grp + 48;
    float a0[8], a1[8], a2[8], a3[8];
#pragma unroll
    for (int q = 0; q < 8; ++q) { a0[q] = 0.f; a1[q] = 0.f; a2[q] = 0.f; a3[q] = 0.f; }
    if (n0 < nLoc) bfadd(a0, Xb[(size_t)(nodeBase + n0) * 16 + lane]);  // self
    if (n1 < nLoc) bfadd(a1, Xb[(size_t)(nodeBase + n1) * 16 + lane]);
    if (n2 < nLoc) bfadd(a2, Xb[(size_t)(nodeBase + n2) * 16 + lane]);
    if (n3 < nLoc) bfadd(a3, Xb[(size_t)(nodeBase + n3) * 16 + lane]);

    for (int s = 0; s < NSLAB; ++s) {
        const int kb = s * SUBNODES;
        int e0 = off[kb + n0], x0 = off[kb + n0 + 1];
        int e1 = off[kb + n1], x1 = off[kb + n1 + 1];
        int e2 = off[kb + n2], x2 = off[kb + n2 + 1];
        int e3 = off[kb + n3], x3 = off[kb + n3 + 1];
        int m = max(max(x0 - e0, x1 - e1), max(x2 - e2, x3 - e3));
        for (int t = 0; t < m; ++t) {
            if (e0 + t < x0) bfadd(a0, Xb[(size_t)srt[e0 + t] * 16 + lane]);
            if (e1 + t < x1) bfadd(a1, Xb[(size_t)srt[e1 + t] * 16 + lane]);
            if (e2 + t < x2) bfadd(a2, Xb[(size_t)srt[e2 + t] * 16 + lane]);
            if (e3 + t < x3) bfadd(a3, Xb[(size_t)srt[e3 + t] * 16 + lane]);
        }
    }

    if (n0 < nLoc) packout(convb, nodeBase + n0, lane, a0);
    if (n1 < nLoc) packout(convb, nodeBase + n1, lane, a1);
    if (n2 < nLoc) packout(convb, nodeBase + n2, lane, a2);
    if (n3 < nLoc) packout(convb, nodeBase + n3, lane, a3);
}

// ---------------------------------------------------------------------------
// Fused MLP via bf16 MFMA (validated R4-R9; H in place in sA, 2 blocks/CU)
// ---------------------------------------------------------------------------
#define TM 128

__global__ __launch_bounds__(256, 2)
void mlp_fused(const unsigned short* __restrict__ convb,
               const unsigned short* __restrict__ w1t, const float* __restrict__ b1,
               const unsigned short* __restrict__ w2t, const float* __restrict__ b2,
               float* __restrict__ out, int N) {
    __shared__ unsigned short sA[TM][136];
    __shared__ unsigned short sW[128][136];

    const int tid  = threadIdx.x;
    const int row0 = blockIdx.x * TM;

    for (int i = tid; i < TM * 16; i += 256) {
        int r = i >> 4, c = i & 15;
        uint4 v = make_uint4(0, 0, 0, 0);
        if (row0 + r < N) v = ((const uint4*)convb)[(size_t)(row0 + r) * 16 + c];
        *(uint4*)&sA[r][c * 8] = v;
    }
    for (int i = tid; i < 128 * 16; i += 256) {
        int r = i >> 4, c = i & 15;
        *(uint4*)&sW[r][c * 8] = ((const uint4*)w1t)[r * 16 + c];
    }
    __syncthreads();

    const int lane = tid & 63;
    const int lrow = lane & 15;
    const int kgrp = lane >> 4;
    const int m0   = (tid >> 6) * 32;

    float bias[8];
#pragma unroll
    for (int nf = 0; nf < 8; ++nf) bias[nf] = b1[nf * 16 + lrow];

    f32x4 acc[2][8] = {};
#pragma unroll
    for (int kk = 0; kk < 128; kk += 32) {
        bf16x8 a0 = *(const bf16x8*)&sA[m0 + lrow][kk + kgrp * 8];
        bf16x8 a1 = *(const bf16x8*)&sA[m0 + 16 + lrow][kk + kgrp * 8];
#pragma unroll
        for (int nf = 0; nf < 8; ++nf) {
            bf16x8 b = *(const bf16x8*)&sW[nf * 16 + lrow][kk + kgrp * 8];
            acc[0][nf] = __builtin_amdgcn_mfma_f32_16x16x32_bf16(a0, b, acc[0][nf], 0, 0, 0);
            acc[1][nf] = __builtin_amdgcn_mfma_f32_16x16x32_bf16(a1, b, acc[1][nf], 0, 0, 0);
        }
    }

    // layer-1 epilogue: relu -> bf16 -> back into sA (own rows only)
#pragma unroll
    for (int mf = 0; mf < 2; ++mf)
#pragma unroll
        for (int nf = 0; nf < 8; ++nf)
#pragma unroll
            for (int r = 0; r < 4; ++r) {
                int row = m0 + mf * 16 + kgrp * 4 + r;
                int col = nf * 16 + lrow;
                float h = fmaxf(acc[mf][nf][r] + bias[nf], 0.f);
                sA[row][col] = f2bf(h);
            }

    __syncthreads();   // all waves past MFMA1 reads of sW; sA(H) complete

    // reload sW <- W2^T
    for (int i = tid; i < 128 * 16; i += 256) {
        int r = i >> 4, c = i & 15;
        *(uint4*)&sW[r][c * 8] = ((const uint4*)w2t)[r * 16 + c];
    }
#pragma unroll
    for (int nf = 0; nf < 8; ++nf) bias[nf] = b2[nf * 16 + lrow];
#pragma unroll
    for (int mf = 0; mf < 2; ++mf)
#pragma unroll
        for (int nf = 0; nf < 8; ++nf) acc[mf][nf] = (f32x4){0.f, 0.f, 0.f, 0.f};
    __syncthreads();

#pragma unroll
    for (int kk = 0; kk < 128; kk += 32) {
        bf16x8 a0 = *(const bf16x8*)&sA[m0 + lrow][kk + kgrp * 8];
        bf16x8 a1 = *(const bf16x8*)&sA[m0 + 16 + lrow][kk + kgrp * 8];
#pragma unroll
        for (int nf = 0; nf < 8; ++nf) {
            bf16x8 b = *(const bf16x8*)&sW[nf * 16 + lrow][kk + kgrp * 8];
            acc[0][nf] = __builtin_amdgcn_mfma_f32_16x16x32_bf16(a0, b, acc[0][nf], 0, 0, 0);
            acc[1][nf] = __builtin_amdgcn_mfma_f32_16x16x32_bf16(a1, b, acc[1][nf], 0, 0, 0);
        }
    }

    // layer-2 epilogue: relu -> fp32 global
#pragma unroll
    for (int mf = 0; mf < 2; ++mf)
#pragma unroll
        for (int nf = 0; nf < 8; ++nf)
#pragma unroll
            for (int r = 0; r < 4; ++r) {
                int row = row0 + m0 + mf * 16 + kgrp * 4 + r;
                int col = nf * 16 + lrow;
                if (row < N)
                    out[(size_t)row * 128 + col] = fmaxf(acc[mf][nf][r] + bias[nf], 0.f);
            }
}

// ---------------------------------------------------------------------------
extern "C" void kernel_launch(void* const* d_in, const int* in_sizes, int n_in,
                              void* d_out, int out_size, void* d_ws, size_t ws_size,
                              hipStream_t stream) {
    const float* X    = (const float*)d_in[0];
    const int*   refA = (const int*)d_in[1];   // dst per edge
    const int*   refB = (const int*)d_in[2];   // src per edge
    const float* w1   = (const float*)d_in[3];
    const float* b1   = (const float*)d_in[4];
    const float* w2   = (const float*)d_in[5];
    const float* b2   = (const float*)d_in[6];
    float* out = (float*)d_out;

    const int nNodes = in_sizes[0] / DFEAT;    // 100000
    const int nE     = in_sizes[1];            // 3200000

    // Workspace layout with liveness-based aliasing:
    //   Xb       : 25.6 MB  (live: prep -> sort_aggregate)
    //   convb    : 25.6 MB  -- ALIASES bedges (13.3 MB). bedges live A->B only;
    //              convb born in pass C. Never simultaneously live.
    //   sub_edges: 16.1 MB  (live: B -> C; disjoint from convb)
    //   w1t/w2t, bcur+scur2 (zeroed inside prep_all)
    char* ws = (char*)d_ws;
    unsigned short* Xb    = (unsigned short*)ws;  ws += (size_t)nNodes * DFEAT * 2;
    unsigned short* convb = (unsigned short*)ws;
    unsigned* bedges      = (unsigned*)convb;     // alias (see above)
    ws += (size_t)nNodes * DFEAT * 2;             // 25.6 MB covers bedges' 13.3 MB
    unsigned* sub_edges = (unsigned*)ws;          ws += (size_t)NSB * SUBCAP * 4;
    unsigned short* w1t = (unsigned short*)ws;    ws += 16384 * 2;
    unsigned short* w2t = (unsigned short*)ws;    ws += 16384 * 2;
    int* bcur  = (int*)ws;                        ws += 64 * 4;
    int* scur2 = (int*)ws;

    // 0) fused prep: x2bf + wprep + zero(bcur,scur2)
    int n8  = nNodes * DFEAT / 8;
    int n8b = (n8 + 255) / 256;
    prep_all<<<n8b + 128 + 1, 256, 0, stream>>>((const float4*)X, (uint4*)Xb, n8, n8b,
                                                w1, w2, w1t, w2t, bcur);

    // 1) two-level edge partition (no global CSR)
    int pBlocks = (nE + CHUNK - 1) / CHUNK;
    partition_edges<<<pBlocks, 256, 0, stream>>>(refA, refB, bcur, bedges, nE);
    partition_sub<<<(BUCKET_CAP / CHUNK + 1) * NBKT, 256, 0, stream>>>(
        bedges, bcur, scur2, sub_edges);

    // 2) fused counting-sort (slab-major) + pull aggregation
    sort_aggregate<<<NSB, 256, 0, stream>>>(sub_edges, scur2,
                                            (const uint4*)Xb, (uint4*)convb);

    // 3+4) fused MLP via bf16 MFMA
    int mBlocks = (nNodes + TM - 1) / TM;
    mlp_fused<<<mBlocks, 256, 0, stream>>>(convb, w1t, b1, w2t, b2, out, nNodes);
}